// Round 6
// baseline (226.809 us; speedup 1.0000x reference)
//
#include <hip/hip_runtime.h>
#include <hip/hip_bf16.h>

#define HDIM 1024
#define SEQ 2048
#define BATCH 16
#define M_TOT (SEQ*BATCH)   // 32768
#define NBLK 4              // N split into 4 chunks of 256
#define BM 256
#define BN 256
#define BKT 64              // K-tile depth
#define NT (HDIM/BKT)       // 16 K-tiles

typedef __attribute__((ext_vector_type(8))) short short8;
typedef __attribute__((ext_vector_type(4))) float f32x4;

typedef const void __attribute__((address_space(1))) gvoid_t;
typedef void __attribute__((address_space(3))) svoid_t;
#define GLD16(gp, lp) __builtin_amdgcn_global_load_lds((gvoid_t*)(gp), (svoid_t*)(lp), 16, 0, 0)
#define VMC(N) asm volatile("s_waitcnt vmcnt(" #N ")" ::: "memory")
#define LGKM0 asm volatile("s_waitcnt lgkmcnt(0)" ::: "memory")

static __device__ __forceinline__ unsigned short f2bf(float f) {
    unsigned int x = __float_as_uint(f);
    unsigned int r = (x + 0x7FFFu + ((x >> 16) & 1u)) >> 16;  // RNE
    return (unsigned short)r;
}

// ---------------- kernel 1: q[b][k] = sum_h hidden[b][h]*Wh[k][h] + attn_b[k] ----------------
__global__ __launch_bounds__(256) void qk_kernel(const float* __restrict__ hidden,
                                                 const float* __restrict__ attn_w,
                                                 const float* __restrict__ attn_b,
                                                 float* __restrict__ q) {
    int k = blockIdx.x;
    int tid = threadIdx.x;
    const float* w = attn_w + (size_t)k * (2 * HDIM);
    float p[BATCH];
#pragma unroll
    for (int b = 0; b < BATCH; b++) p[b] = 0.f;
    for (int h = tid; h < HDIM; h += 256) {
        float wv = w[h];
#pragma unroll
        for (int b = 0; b < BATCH; b++) p[b] += hidden[b * HDIM + h] * wv;
    }
#pragma unroll
    for (int b = 0; b < BATCH; b++) {
        for (int off = 32; off; off >>= 1) p[b] += __shfl_down(p[b], off);
    }
    __shared__ float red[4][BATCH];
    int lane = tid & 63, wid = tid >> 6;
    if (lane == 0) {
#pragma unroll
        for (int b = 0; b < BATCH; b++) red[wid][b] = p[b];
    }
    __syncthreads();
    if (tid < BATCH) {
        float s = red[0][tid] + red[1][tid] + red[2][tid] + red[3][tid] + attn_b[k];
        q[(size_t)tid * HDIM + k] = s;
    }
}

// ---------------- kernel 2: We fp32 -> bf16, layout web[n][h] ----------------
__global__ __launch_bounds__(256) void conv_kernel(const float* __restrict__ attn_w,
                                                   __hip_bfloat16* __restrict__ web) {
    size_t i0 = ((size_t)blockIdx.x * 256 + threadIdx.x) * 8;
    int n = (int)(i0 >> 10);
    int h = (int)(i0 & 1023);
    const float4* src = reinterpret_cast<const float4*>(attn_w + (size_t)n * (2 * HDIM) + HDIM + h);
    float4 a = src[0], b = src[1];
    union { unsigned short u[8]; short8 v; } cv;
    cv.u[0] = f2bf(a.x); cv.u[1] = f2bf(a.y); cv.u[2] = f2bf(a.z); cv.u[3] = f2bf(a.w);
    cv.u[4] = f2bf(b.x); cv.u[5] = f2bf(b.y); cv.u[6] = f2bf(b.z); cv.u[7] = f2bf(b.w);
    *reinterpret_cast<short8*>((unsigned short*)web + i0) = cv.v;
}

// ---------------- kernel 3: 8-phase 256x256 GEMM, A = fp32 fused-convert, + fused epilogue ----
// LDS map (bytes): A[par][half] = par*32768 + half*16384 ; B[par][half] = 65536 + same. 128KB.
// Swizzle involution within each 128B row: byte ^= ((row&7)<<4).
//   B: pre-swizzled GLOBAL source + linear gload_lds dest.  A: swizzled ds_write.  Reads: swizzled.
__global__ __launch_bounds__(512, 2) void gemm8(const float* __restrict__ enc,
                                                const __hip_bfloat16* __restrict__ web,
                                                const float* __restrict__ qv,
                                                const float* __restrict__ score_w,
                                                float* __restrict__ part) {
    __shared__ __align__(16) char pool[131072];

    int tid = threadIdx.x;
    int lane = tid & 63;
    int wid = tid >> 6;        // 0..7
    int wr = wid >> 2;         // 0..1  M half
    int wc = wid & 3;          // 0..3  N quarter

    // XCD-bijective swizzle: 512 blocks = 8 XCDs x 64; same-bm (A-panel) blocks contiguous per XCD
    int bid = blockIdx.x;
    int lin = (bid & 7) * 64 + (bid >> 3);
    int bm = lin >> 2;         // 0..127
    int bn = lin & 3;          // 0..3
    int m0 = bm * BM, n0 = bn * BN;

    // ---- B staging constants (pre-swizzled global source, linear LDS dest) ----
    int srow = tid >> 3;                                   // 0..63
    int scolb = (((tid & 7) ^ ((tid >> 3) & 7)) << 4);     // swizzled byte col 0..127
    const char* wb = (const char*)web;

    auto STG = [&](const char* g, int ldsoff) {
        GLD16(g + (size_t)srow * 2048 + scolb, pool + ldsoff + wid * 1024);
        GLD16(g + (size_t)(srow + 64) * 2048 + scolb, pool + ldsoff + 8192 + wid * 1024);
    };
    auto BPTR = [&](int kt, int h) { return wb + ((size_t)(n0 + h * 128) * HDIM + kt * BKT) * 2; };
#define ALDS(par, h) ((par) * 32768 + (h) * 16384)
#define BLDS(par, h) (65536 + (par) * 32768 + (h) * 16384)

    // ---- A staging constants (fp32 load -> regs -> cvt -> swizzled ds_write) ----
    int ar = tid >> 2;                 // 0..127 row within half
    int ac = (tid & 3) * 16;           // f32 col within K-tile
    int awc = ((tid & 3) * 32) ^ ((ar & 7) << 4);   // swizzled byte col for first b128
    float4 av_e[8], av_o[8];           // even/odd tile in flight: [0..3]=half0, [4..7]=half1

    auto ALD = [&](float4* d, int kt, int h) {
        const float4* p = reinterpret_cast<const float4*>(enc + (size_t)(m0 + h * 128 + ar) * HDIM + kt * BKT + ac);
        d[0] = p[0]; d[1] = p[1]; d[2] = p[2]; d[3] = p[3];
    };
    auto AWR = [&](float4* v, int par) {
#pragma unroll
        for (int h = 0; h < 2; ++h) {
            const float4* s4 = v + h * 4;
            union { __hip_bfloat162 b[4]; short8 s; } w0, w1;
            w0.b[0] = __float22bfloat162_rn(make_float2(s4[0].x, s4[0].y));
            w0.b[1] = __float22bfloat162_rn(make_float2(s4[0].z, s4[0].w));
            w0.b[2] = __float22bfloat162_rn(make_float2(s4[1].x, s4[1].y));
            w0.b[3] = __float22bfloat162_rn(make_float2(s4[1].z, s4[1].w));
            w1.b[0] = __float22bfloat162_rn(make_float2(s4[2].x, s4[2].y));
            w1.b[1] = __float22bfloat162_rn(make_float2(s4[2].z, s4[2].w));
            w1.b[2] = __float22bfloat162_rn(make_float2(s4[3].x, s4[3].y));
            w1.b[3] = __float22bfloat162_rn(make_float2(s4[3].z, s4[3].w));
            char* base = pool + par * 32768 + h * 16384 + ar * 128;
            *reinterpret_cast<short8*>(base + awc) = w0.s;
            *reinterpret_cast<short8*>(base + (awc ^ 16)) = w1.s;
        }
    };

    // ---- fragment-read constants (swizzled ds_read addresses) ----
    int lq = lane & 15, lh = lane >> 4;
    int flip = (lane & 7) << 4;
    int pks0 = lq * 128 + ((lh * 16) ^ flip);
    int pks1 = lq * 128 + (((64 + lh * 16)) ^ flip);
    int aFB = wr * 16384;                                   // + par*32768
    int bFB = 65536 + (wc >> 1) * 16384 + (wc & 1) * 8192;  // + par*32768

    f32x4 acc[8][4];
#pragma unroll
    for (int i = 0; i < 8; i++)
#pragma unroll
        for (int j = 0; j < 4; j++) acc[i][j] = (f32x4)0.f;
    short8 br[4][2];

#define RD8(off) (*reinterpret_cast<const short8*>(pool + (off)))

#define PHASE(Q, PAR, STAGE_STMT, PRE_CLOSE)                                              \
    {                                                                                     \
        if ((Q) == 0) {                                                                   \
            _Pragma("unroll") for (int nj = 0; nj < 4; ++nj) {                            \
                br[nj][0] = RD8(bFB + (PAR) * 32768 + nj * 2048 + pks0);                  \
                br[nj][1] = RD8(bFB + (PAR) * 32768 + nj * 2048 + pks1);                  \
            }                                                                             \
        }                                                                                 \
        short8 a0k0 = RD8(aFB + (PAR) * 32768 + (2 * (Q)) * 2048 + pks0);                 \
        short8 a0k1 = RD8(aFB + (PAR) * 32768 + (2 * (Q)) * 2048 + pks1);                 \
        short8 a1k0 = RD8(aFB + (PAR) * 32768 + (2 * (Q) + 1) * 2048 + pks0);             \
        short8 a1k1 = RD8(aFB + (PAR) * 32768 + (2 * (Q) + 1) * 2048 + pks1);             \
        STAGE_STMT;                                                                       \
        __builtin_amdgcn_s_barrier();                                                     \
        __builtin_amdgcn_s_setprio(1);                                                    \
        _Pragma("unroll") for (int nj = 0; nj < 4; ++nj) {                                \
            acc[2 * (Q)][nj] = __builtin_amdgcn_mfma_f32_16x16x32_bf16(a0k0, br[nj][0], acc[2 * (Q)][nj], 0, 0, 0); \
            acc[2 * (Q)][nj] = __builtin_amdgcn_mfma_f32_16x16x32_bf16(a0k1, br[nj][1], acc[2 * (Q)][nj], 0, 0, 0); \
            acc[2 * (Q) + 1][nj] = __builtin_amdgcn_mfma_f32_16x16x32_bf16(a1k0, br[nj][0], acc[2 * (Q) + 1][nj], 0, 0, 0); \
            acc[2 * (Q) + 1][nj] = __builtin_amdgcn_mfma_f32_16x16x32_bf16(a1k1, br[nj][1], acc[2 * (Q) + 1][nj], 0, 0, 0); \
        }                                                                                 \
        __builtin_amdgcn_s_setprio(0);                                                    \
        PRE_CLOSE;                                                                        \
        __builtin_amdgcn_s_barrier();                                                     \
        __builtin_amdgcn_sched_barrier(0);                                                \
    }

    // ---- prologue ----
    // loads: A(0) 8, B(0) 4 ; wait A(0); write ALDS(0); loads A(1) 8, B(1) 4 ; wait B(0).
    ALD(av_o, 0, 0);
    ALD(av_o + 4, 0, 1);
    STG(BPTR(0, 0), BLDS(0, 0));
    STG(BPTR(0, 1), BLDS(0, 1));
    VMC(4);
    AWR(av_o, 0);
    ALD(av_o, 1, 0);
    ALD(av_o + 4, 1, 1);
    STG(BPTR(1, 0), BLDS(1, 0));
    STG(BPTR(1, 1), BLDS(1, 1));
    VMC(12);
    LGKM0;
    __builtin_amdgcn_s_barrier();
    __builtin_amdgcn_sched_barrier(0);

    // ---- main loop: J=0..6, tiles k0=2J (PAR0), k1=2J+1 (PAR1) ----
    // entry invariant: ALDS0=A(2J) written, BLDS0=B(2J) landed; in flight: A(2J+1) regs(8), B(2J+1)(4)
#pragma unroll 1
    for (int J = 0; J < 7; ++J) {
        int ke = 2 * J + 2, ko = 2 * J + 3;
        PHASE(0, 0, ALD(av_e, ke, 0), );                               // +4 A-even h0
        PHASE(1, 0, ALD(av_e + 4, ke, 1), );                           // +4 A-even h1
        PHASE(2, 0, { VMC(8); AWR(av_o, 1); }, LGKM0);                 // drain A(odd)+B(odd); write ALDS1
        PHASE(3, 0, { STG(BPTR(ke, 0), BLDS(0, 0)); STG(BPTR(ke, 1), BLDS(0, 1)); }, );  // +4 B-even
        PHASE(0, 1, ALD(av_o, ko, 0), );                               // +4 A-odd h0
        PHASE(1, 1, ALD(av_o + 4, ko, 1), );                           // +4 A-odd h1
        PHASE(2, 1, { VMC(8); AWR(av_e, 0); }, LGKM0);                 // drain A(even)+B(even); write ALDS0
        PHASE(3, 1, { STG(BPTR(ko, 0), BLDS(1, 0)); STG(BPTR(ko, 1), BLDS(1, 1)); }, );  // +4 B-odd
    }
    // ---- peeled last iter (tiles 14,15) ----
    PHASE(0, 0, , );
    PHASE(1, 0, , );
    PHASE(2, 0, { VMC(0); AWR(av_o, 1); }, LGKM0);                     // A(15)+B(15) drained; write ALDS1
    PHASE(3, 0, , );
    PHASE(0, 1, , );
    PHASE(1, 1, , );
    PHASE(2, 1, , );
    PHASE(3, 1, , );

    // ---- fused epilogue (aliases pool) ----
    float* q_lds = reinterpret_cast<float*>(pool);            // [16][256]
    float* sc_lds = reinterpret_cast<float*>(pool + 16384);   // [256]
    float* eng = reinterpret_cast<float*>(pool + 17408);      // [4][256]
    {
        int qb = tid >> 5;            // 0..15
        int kl = (tid & 31) * 8;      // 0..248
        const float4* src = reinterpret_cast<const float4*>(qv + (size_t)qb * HDIM + n0 + kl);
        float4 v0 = src[0], v1 = src[1];
        *reinterpret_cast<float4*>(&q_lds[qb * 256 + kl]) = v0;
        *reinterpret_cast<float4*>(&q_lds[qb * 256 + kl + 4]) = v1;
        if (tid < BN) sc_lds[tid] = score_w[n0 + tid];
    }
    __syncthreads();

#pragma unroll
    for (int mi = 0; mi < 8; ++mi) {
#pragma unroll
        for (int r = 0; r < 4; ++r) {
            int b = lh * 4 + r;       // row-within-16 == batch index
            float s = 0.f;
#pragma unroll
            for (int nj = 0; nj < 4; ++nj) {
                int kl = wc * 64 + nj * 16 + lq;
                float v = acc[mi][nj][r] + q_lds[b * 256 + kl];
                float t = 1.f - 2.f / (__expf(2.f * v) + 1.f);  // tanh(v)
                s += sc_lds[kl] * t;
            }
            for (int off = 1; off < 16; off <<= 1) s += __shfl_xor(s, off);
            if (lq == 0) eng[wc * 256 + wr * 128 + mi * 16 + b] = s;
        }
    }
    __syncthreads();
    if (tid < BM) {
        float s = eng[tid] + eng[256 + tid] + eng[512 + tid] + eng[768 + tid];
        part[(size_t)bn * M_TOT + m0 + tid] = s;
    }
#undef PHASE
#undef RD8
#undef ALDS
#undef BLDS
}

// ---------------- kernel 4: reduce partials + mask + softmax over S ----------------
__global__ __launch_bounds__(256) void softmax_kernel(const float* __restrict__ part,
                                                      const int* __restrict__ mask,
                                                      float* __restrict__ out) {
    int b = blockIdx.x;
    int tid = threadIdx.x;
    __shared__ float e_lds[SEQ];
    __shared__ float red[4], red2[4];
    int lane = tid & 63, wid = tid >> 6;
    float lmax = -3.4e38f;
    for (int it = 0; it < SEQ / 256; ++it) {
        int s = it * 256 + tid;
        size_t m = (size_t)s * BATCH + b;
        float e = 0.f;
#pragma unroll
        for (int c = 0; c < NBLK; c++) e += part[(size_t)c * M_TOT + m];
        if (mask[(size_t)b * SEQ + s]) e = -1e12f;
        e_lds[s] = e;
        lmax = fmaxf(lmax, e);
    }
    for (int off = 32; off; off >>= 1) lmax = fmaxf(lmax, __shfl_xor(lmax, off));
    if (lane == 0) red[wid] = lmax;
    __syncthreads();
    float gmax = fmaxf(fmaxf(red[0], red[1]), fmaxf(red[2], red[3]));
    float lsum = 0.f;
    for (int it = 0; it < SEQ / 256; ++it) {
        int s = it * 256 + tid;
        float p = __expf(e_lds[s] - gmax);
        e_lds[s] = p;
        lsum += p;
    }
    for (int off = 32; off; off >>= 1) lsum += __shfl_xor(lsum, off);
    if (lane == 0) red2[wid] = lsum;
    __syncthreads();
    float inv = 1.f / (red2[0] + red2[1] + red2[2] + red2[3]);
    for (int it = 0; it < SEQ / 256; ++it) {
        int s = it * 256 + tid;
        out[(size_t)b * SEQ + s] = e_lds[s] * inv;
    }
}

extern "C" void kernel_launch(void* const* d_in, const int* in_sizes, int n_in,
                              void* d_out, int out_size, void* d_ws, size_t ws_size,
                              hipStream_t stream) {
    const float* hidden   = (const float*)d_in[0];
    const float* enc      = (const float*)d_in[1];
    const int*   seq_mask = (const int*)d_in[2];
    const float* attn_w   = (const float*)d_in[3];
    const float* attn_b   = (const float*)d_in[4];
    const float* score_w  = (const float*)d_in[5];
    float* out = (float*)d_out;

    char* ws = (char*)d_ws;
    float* q = (float*)ws;                                        // 64 KB
    __hip_bfloat16* web = (__hip_bfloat16*)(ws + 65536);          // 2 MB
    float* part = (float*)(ws + 65536 + 2 * 1024 * 1024);         // 512 KB

    conv_kernel<<<dim3((HDIM * HDIM) / (8 * 256)), dim3(256), 0, stream>>>(attn_w, web);
    qk_kernel<<<dim3(HDIM), dim3(256), 0, stream>>>(hidden, attn_w, attn_b, q);
    gemm8<<<dim3(NBLK * (M_TOT / BM)), dim3(512), 0, stream>>>(enc, web, q, score_w, part);
    softmax_kernel<<<dim3(BATCH), dim3(256), 0, stream>>>(part, seq_mask, out);
}

// Round 7
// 216.748 us; speedup vs baseline: 1.0464x; 1.0464x over previous
//
#include <hip/hip_runtime.h>
#include <hip/hip_bf16.h>

#define HDIM 1024
#define SEQ 2048
#define BATCH 16
#define M_TOT (SEQ*BATCH)   // 32768
#define NBLK 8              // N split into 8 chunks of 128
#define BM 256
#define BN 128
#define BKT 64              // K-tile depth
#define NT (HDIM/BKT)       // 16 K-tiles

typedef __attribute__((ext_vector_type(8))) short short8;
typedef __attribute__((ext_vector_type(4))) float f32x4;

typedef const void __attribute__((address_space(1))) gvoid_t;
typedef void __attribute__((address_space(3))) svoid_t;
#define GLD16(gp, lp) __builtin_amdgcn_global_load_lds((gvoid_t*)(gp), (svoid_t*)(lp), 16, 0, 0)
#define VMC(N) asm volatile("s_waitcnt vmcnt(" #N ")" ::: "memory")
#define LGKM0 asm volatile("s_waitcnt lgkmcnt(0)" ::: "memory")

static __device__ __forceinline__ unsigned short f2bf(float f) {
    unsigned int x = __float_as_uint(f);
    unsigned int r = (x + 0x7FFFu + ((x >> 16) & 1u)) >> 16;  // RNE
    return (unsigned short)r;
}

// ---------------- kernel 1: fused prep = {We fp32->bf16 web[n][h]} + {q[b][k]} ----------------
__global__ __launch_bounds__(256) void prep_kernel(const float* __restrict__ hidden,
                                                   const float* __restrict__ attn_w,
                                                   const float* __restrict__ attn_b,
                                                   float* __restrict__ q,
                                                   __hip_bfloat16* __restrict__ web) {
    int bid = blockIdx.x;
    if (bid < 512) {
        // conv: We fp32 -> bf16
        size_t i0 = ((size_t)bid * 256 + threadIdx.x) * 8;
        int n = (int)(i0 >> 10);
        int h = (int)(i0 & 1023);
        const float4* src = reinterpret_cast<const float4*>(attn_w + (size_t)n * (2 * HDIM) + HDIM + h);
        float4 a = src[0], b = src[1];
        union { unsigned short u[8]; short8 v; } cv;
        cv.u[0] = f2bf(a.x); cv.u[1] = f2bf(a.y); cv.u[2] = f2bf(a.z); cv.u[3] = f2bf(a.w);
        cv.u[4] = f2bf(b.x); cv.u[5] = f2bf(b.y); cv.u[6] = f2bf(b.z); cv.u[7] = f2bf(b.w);
        *reinterpret_cast<short8*>((unsigned short*)web + i0) = cv.v;
        return;
    }
    // qk: q[b][k] = sum_h hidden[b][h]*Wh[k][h] + attn_b[k]
    int k = bid - 512;                // 0..1023
    int tid = threadIdx.x;
    const float* w = attn_w + (size_t)k * (2 * HDIM);
    float p[BATCH];
#pragma unroll
    for (int b = 0; b < BATCH; b++) p[b] = 0.f;
    for (int h = tid; h < HDIM; h += 256) {
        float wv = w[h];
#pragma unroll
        for (int b = 0; b < BATCH; b++) p[b] += hidden[b * HDIM + h] * wv;
    }
#pragma unroll
    for (int b = 0; b < BATCH; b++) {
        for (int off = 32; off; off >>= 1) p[b] += __shfl_down(p[b], off);
    }
    __shared__ float red[4][BATCH];
    int lane = tid & 63, wid = tid >> 6;
    if (lane == 0) {
#pragma unroll
        for (int b = 0; b < BATCH; b++) red[wid][b] = p[b];
    }
    __syncthreads();
    if (tid < BATCH) {
        float s = red[0][tid] + red[1][tid] + red[2][tid] + red[3][tid] + attn_b[k];
        q[(size_t)tid * HDIM + k] = s;
    }
}

// ---------------- kernel 2: 2-phase/tile 256x128 GEMM, A = fp32 fused-convert ----------------
// LDS (bytes): A[par] = par*32768 ([256 rows][128B], XOR-swizzled slots); B[par] = 65536 + par*16384
// ([128 rows][128B]). 96KB total. Swizzle involution per 128B row: slot c (16B) stored at c^(row&7).
__global__ __launch_bounds__(512, 2) void gemm8(const float* __restrict__ enc,
                                                const __hip_bfloat16* __restrict__ web,
                                                const float* __restrict__ qv,
                                                const float* __restrict__ score_w,
                                                float* __restrict__ part) {
    __shared__ __align__(16) char pool[98304];

    int tid = threadIdx.x;
    int lane = tid & 63;
    int wid = tid >> 6;        // 0..7
    int wr = wid >> 1;         // 0..3  M quarter (64 rows)
    int wc = wid & 1;          // 0..1  N half (64 cols)

    // XCD-bijective: 1024 blocks = 8 XCDs x 128; bn fastest -> co-resident share A panels
    int bid = blockIdx.x;
    int lin = (bid & 7) * 128 + (bid >> 3);
    int bm = lin >> 3;         // 0..127
    int bn = lin & 7;          // 0..7
    int m0 = bm * BM, n0 = bn * BN;

    // ---- B staging (gload_lds, pre-swizzled global source, linear LDS dest) ----
    const char* wb = (const char*)web;
    int brow = wid * 8 + (lane >> 3);                       // local row for load0 (0..63)
    int bsegb = (((lane & 7) ^ ((lane >> 3) & 7)) << 4);    // pre-swizzled byte col
    auto BSTG = [&](int kt, int p) {
        const char* g0 = wb + ((size_t)(n0 + brow) * HDIM + kt * BKT) * 2 + bsegb;
        GLD16(g0, pool + 65536 + p * 16384 + wid * 1024);
        const char* g1 = wb + ((size_t)(n0 + 64 + brow) * HDIM + kt * BKT) * 2 + bsegb;
        GLD16(g1, pool + 65536 + p * 16384 + 8192 + wid * 1024);
    };

    // ---- A staging (fp32 -> regs -> cvt -> swizzled ds_write), 1-deep ----
    int arow = tid >> 1;               // 0..255
    int ah = tid & 1;                  // 32-f32 half of the 64-col K-tile
    const float* abase = enc + (size_t)(m0 + arow) * HDIM + ah * 32;
    float4 av[8];
    auto ALD = [&](int kt) {
        const float4* p = reinterpret_cast<const float4*>(abase + kt * BKT);
#pragma unroll
        for (int i = 0; i < 8; i++) av[i] = p[i];
    };
    int ar7 = arow & 7;
    auto AWR = [&](int p) {
        char* base = pool + p * 32768 + arow * 128;
#pragma unroll
        for (int w = 0; w < 4; w++) {
            union { __hip_bfloat162 b[4]; short8 s; } u;
            u.b[0] = __float22bfloat162_rn(make_float2(av[2 * w].x, av[2 * w].y));
            u.b[1] = __float22bfloat162_rn(make_float2(av[2 * w].z, av[2 * w].w));
            u.b[2] = __float22bfloat162_rn(make_float2(av[2 * w + 1].x, av[2 * w + 1].y));
            u.b[3] = __float22bfloat162_rn(make_float2(av[2 * w + 1].z, av[2 * w + 1].w));
            *reinterpret_cast<short8*>(base + (((ah * 4 + w) ^ ar7) << 4)) = u.s;
        }
    };

    // ---- fragment-read constants (swizzled) ----
    int lq = lane & 15, lh = lane >> 4;
    int s0 = ((lh ^ (lq & 7)) << 4);          // ks=0 slot byte
    int s1 = (((4 + lh) ^ (lq & 7)) << 4);    // ks=1 slot byte
    int aRB = (wr * 64 + lq) * 128;           // + par*32768 + mi*2048
    int bRB = 65536 + (wc * 64 + lq) * 128;   // + par*16384 + nj*2048

    f32x4 acc[4][4];
#pragma unroll
    for (int i = 0; i < 4; i++)
#pragma unroll
        for (int j = 0; j < 4; j++) acc[i][j] = (f32x4)0.f;
    short8 br[4][2];

#define RD8(off) (*reinterpret_cast<const short8*>(pool + (off)))

#define PH1(PAR, T)                                                                       \
    {                                                                                     \
        _Pragma("unroll") for (int nj = 0; nj < 4; ++nj) {                                \
            br[nj][0] = RD8(bRB + (PAR) * 16384 + nj * 2048 + s0);                        \
            br[nj][1] = RD8(bRB + (PAR) * 16384 + nj * 2048 + s1);                        \
        }                                                                                 \
        short8 a00 = RD8(aRB + (PAR) * 32768 + 0 * 2048 + s0);                            \
        short8 a01 = RD8(aRB + (PAR) * 32768 + 0 * 2048 + s1);                            \
        short8 a10 = RD8(aRB + (PAR) * 32768 + 1 * 2048 + s0);                            \
        short8 a11 = RD8(aRB + (PAR) * 32768 + 1 * 2048 + s1);                            \
        if ((T) < 15) ALD((T) + 1);                                                       \
        __builtin_amdgcn_s_barrier();                                                     \
        __builtin_amdgcn_s_setprio(1);                                                    \
        _Pragma("unroll") for (int nj = 0; nj < 4; ++nj) {                                \
            acc[0][nj] = __builtin_amdgcn_mfma_f32_16x16x32_bf16(a00, br[nj][0], acc[0][nj], 0, 0, 0); \
            acc[0][nj] = __builtin_amdgcn_mfma_f32_16x16x32_bf16(a01, br[nj][1], acc[0][nj], 0, 0, 0); \
            acc[1][nj] = __builtin_amdgcn_mfma_f32_16x16x32_bf16(a10, br[nj][0], acc[1][nj], 0, 0, 0); \
            acc[1][nj] = __builtin_amdgcn_mfma_f32_16x16x32_bf16(a11, br[nj][1], acc[1][nj], 0, 0, 0); \
        }                                                                                 \
        __builtin_amdgcn_s_setprio(0);                                                    \
        __builtin_amdgcn_s_barrier();                                                     \
        __builtin_amdgcn_sched_barrier(0);                                                \
    }

#define PH2(PAR, T)                                                                       \
    {                                                                                     \
        short8 a00 = RD8(aRB + (PAR) * 32768 + 2 * 2048 + s0);                            \
        short8 a01 = RD8(aRB + (PAR) * 32768 + 2 * 2048 + s1);                            \
        short8 a10 = RD8(aRB + (PAR) * 32768 + 3 * 2048 + s0);                            \
        short8 a11 = RD8(aRB + (PAR) * 32768 + 3 * 2048 + s1);                            \
        VMC(0);                                                                           \
        if ((T) < 15) AWR((PAR) ^ 1);                                                     \
        if ((T) < 14) BSTG((T) + 2, (PAR));                                               \
        LGKM0;                                                                            \
        __builtin_amdgcn_sched_barrier(0);                                                \
        __builtin_amdgcn_s_barrier();                                                     \
        __builtin_amdgcn_s_setprio(1);                                                    \
        _Pragma("unroll") for (int nj = 0; nj < 4; ++nj) {                                \
            acc[2][nj] = __builtin_amdgcn_mfma_f32_16x16x32_bf16(a00, br[nj][0], acc[2][nj], 0, 0, 0); \
            acc[2][nj] = __builtin_amdgcn_mfma_f32_16x16x32_bf16(a01, br[nj][1], acc[2][nj], 0, 0, 0); \
            acc[3][nj] = __builtin_amdgcn_mfma_f32_16x16x32_bf16(a10, br[nj][0], acc[3][nj], 0, 0, 0); \
            acc[3][nj] = __builtin_amdgcn_mfma_f32_16x16x32_bf16(a11, br[nj][1], acc[3][nj], 0, 0, 0); \
        }                                                                                 \
        __builtin_amdgcn_s_setprio(0);                                                    \
        __builtin_amdgcn_s_barrier();                                                     \
        __builtin_amdgcn_sched_barrier(0);                                                \
    }

    // ---- prologue: A(0) -> ALDS(0); B(0)->BLDS(0), B(1)->BLDS(1) in flight ----
    ALD(0);
    VMC(0);
    AWR(0);
    BSTG(0, 0);
    BSTG(1, 1);
    VMC(2);            // drain B(0); B(1) stays in flight
    LGKM0;             // A(0) writes visible
    __builtin_amdgcn_s_barrier();
    __builtin_amdgcn_sched_barrier(0);

    // ---- main loop: 16 tiles, 2 phases each ----
#pragma unroll 1
    for (int tp = 0; tp < 8; ++tp) {
        int t0 = 2 * tp, t1 = 2 * tp + 1;
        PH1(0, t0);
        PH2(0, t0);
        PH1(1, t1);
        PH2(1, t1);
    }

    // ---- fused epilogue (aliases pool) ----
    float* q_lds = reinterpret_cast<float*>(pool);            // [16][128]
    float* sc_lds = reinterpret_cast<float*>(pool + 8192);    // [128]
    float* eng = reinterpret_cast<float*>(pool + 8704);       // [2][256]
    {
        int qb = tid >> 5;            // 0..15
        int kl = (tid & 31) * 4;      // 0..124
        *reinterpret_cast<float4*>(&q_lds[qb * 128 + kl]) =
            *reinterpret_cast<const float4*>(qv + (size_t)qb * HDIM + n0 + kl);
        if (tid < BN) sc_lds[tid] = score_w[n0 + tid];
    }
    __syncthreads();

#pragma unroll
    for (int mi = 0; mi < 4; ++mi) {
#pragma unroll
        for (int r = 0; r < 4; ++r) {
            int b = lh * 4 + r;       // row-within-16 == batch index (M = s*16 + b)
            float s = 0.f;
#pragma unroll
            for (int nj = 0; nj < 4; ++nj) {
                int kl = wc * 64 + nj * 16 + lq;
                float v = acc[mi][nj][r] + q_lds[b * 128 + kl];
                float t = 1.f - 2.f / (__expf(2.f * v) + 1.f);  // tanh(v)
                s += sc_lds[kl] * t;
            }
            for (int off = 1; off < 16; off <<= 1) s += __shfl_xor(s, off);
            if (lq == 0) eng[wc * 256 + wr * 64 + mi * 16 + b] = s;
        }
    }
    __syncthreads();
    if (tid < BM) part[(size_t)bn * M_TOT + m0 + tid] = eng[tid] + eng[256 + tid];
#undef PH1
#undef PH2
#undef RD8
}

// ---------------- kernel 3: reduce partials + mask + softmax over S ----------------
__global__ __launch_bounds__(256) void softmax_kernel(const float* __restrict__ part,
                                                      const int* __restrict__ mask,
                                                      float* __restrict__ out) {
    int b = blockIdx.x;
    int tid = threadIdx.x;
    __shared__ float e_lds[SEQ];
    __shared__ float red[4], red2[4];
    int lane = tid & 63, wid = tid >> 6;
    float lmax = -3.4e38f;
    for (int it = 0; it < SEQ / 256; ++it) {
        int s = it * 256 + tid;
        size_t m = (size_t)s * BATCH + b;
        float e = 0.f;
#pragma unroll
        for (int c = 0; c < NBLK; c++) e += part[(size_t)c * M_TOT + m];
        if (mask[(size_t)b * SEQ + s]) e = -1e12f;
        e_lds[s] = e;
        lmax = fmaxf(lmax, e);
    }
    for (int off = 32; off; off >>= 1) lmax = fmaxf(lmax, __shfl_xor(lmax, off));
    if (lane == 0) red[wid] = lmax;
    __syncthreads();
    float gmax = fmaxf(fmaxf(red[0], red[1]), fmaxf(red[2], red[3]));
    float lsum = 0.f;
    for (int it = 0; it < SEQ / 256; ++it) {
        int s = it * 256 + tid;
        float p = __expf(e_lds[s] - gmax);
        e_lds[s] = p;
        lsum += p;
    }
    for (int off = 32; off; off >>= 1) lsum += __shfl_xor(lsum, off);
    if (lane == 0) red2[wid] = lsum;
    __syncthreads();
    float inv = 1.f / (red2[0] + red2[1] + red2[2] + red2[3]);
    for (int it = 0; it < SEQ / 256; ++it) {
        int s = it * 256 + tid;
        out[(size_t)b * SEQ + s] = e_lds[s] * inv;
    }
}

extern "C" void kernel_launch(void* const* d_in, const int* in_sizes, int n_in,
                              void* d_out, int out_size, void* d_ws, size_t ws_size,
                              hipStream_t stream) {
    const float* hidden   = (const float*)d_in[0];
    const float* enc      = (const float*)d_in[1];
    const int*   seq_mask = (const int*)d_in[2];
    const float* attn_w   = (const float*)d_in[3];
    const float* attn_b   = (const float*)d_in[4];
    const float* score_w  = (const float*)d_in[5];
    float* out = (float*)d_out;

    char* ws = (char*)d_ws;
    float* q = (float*)ws;                                        // 64 KB
    __hip_bfloat16* web = (__hip_bfloat16*)(ws + 65536);          // 2 MB
    float* part = (float*)(ws + 65536 + 2 * 1024 * 1024);         // 1 MB

    prep_kernel<<<dim3(512 + HDIM), dim3(256), 0, stream>>>(hidden, attn_w, attn_b, q, web);
    gemm8<<<dim3(NBLK * (M_TOT / BM)), dim3(512), 0, stream>>>(enc, web, q, score_w, part);
    softmax_kernel<<<dim3(BATCH), dim3(256), 0, stream>>>(part, seq_mask, out);
}

// Round 8
// 120.727 us; speedup vs baseline: 1.8787x; 1.7954x over previous
//
#include <hip/hip_runtime.h>
#include <hip/hip_bf16.h>

#define HDIM 1024
#define SEQ 2048
#define BATCH 16
#define M_TOT (SEQ*BATCH)   // 32768
#define NBLK 4              // N split into 4 chunks of 256
#define BM 256
#define BN 256
#define BKT 64              // K-tile depth
#define NT (HDIM/BKT)       // 16 K-tiles

// prep_all grid layout
#define NB_ENC ((M_TOT*HDIM)/(8*256))   // 16384
#define NB_WE  ((HDIM*HDIM)/(8*256))    // 512
#define NB_QK  (HDIM)                   // 1024

typedef __attribute__((ext_vector_type(8))) short short8;
typedef __attribute__((ext_vector_type(4))) float f32x4;

typedef const void __attribute__((address_space(1))) gvoid_t;
typedef void __attribute__((address_space(3))) svoid_t;
#define GLD16(gp, lp) __builtin_amdgcn_global_load_lds((gvoid_t*)(gp), (svoid_t*)(lp), 16, 0, 0)
#define VMC(N) asm volatile("s_waitcnt vmcnt(" #N ")" ::: "memory")

static __device__ __forceinline__ unsigned short f2bf(float f) {
    unsigned int x = __float_as_uint(f);
    unsigned int r = (x + 0x7FFFu + ((x >> 16) & 1u)) >> 16;  // RNE
    return (unsigned short)r;
}

// ---------------- kernel 1: fused prep = conv_enc + conv_we + qk ----------------
__global__ __launch_bounds__(256) void prep_all(const float* __restrict__ hidden,
                                                const float* __restrict__ enc,
                                                const float* __restrict__ attn_w,
                                                const float* __restrict__ attn_b,
                                                float* __restrict__ q,
                                                __hip_bfloat16* __restrict__ web,
                                                __hip_bfloat16* __restrict__ encb) {
    int bid = blockIdx.x;
    if (bid < NB_ENC) {
        // enc fp32 -> bf16 (row-major [M_TOT][H])
        size_t i0 = ((size_t)bid * 256 + threadIdx.x) * 8;
        const float4* s = reinterpret_cast<const float4*>(enc + i0);
        float4 a = s[0], b = s[1];
        union { unsigned short u[8]; short8 v; } cv;
        cv.u[0] = f2bf(a.x); cv.u[1] = f2bf(a.y); cv.u[2] = f2bf(a.z); cv.u[3] = f2bf(a.w);
        cv.u[4] = f2bf(b.x); cv.u[5] = f2bf(b.y); cv.u[6] = f2bf(b.z); cv.u[7] = f2bf(b.w);
        *reinterpret_cast<short8*>((unsigned short*)encb + i0) = cv.v;
        return;
    }
    if (bid < NB_ENC + NB_WE) {
        // We fp32 -> bf16, layout web[n][h]
        size_t i0 = ((size_t)(bid - NB_ENC) * 256 + threadIdx.x) * 8;
        int n = (int)(i0 >> 10);
        int h = (int)(i0 & 1023);
        const float4* src = reinterpret_cast<const float4*>(attn_w + (size_t)n * (2 * HDIM) + HDIM + h);
        float4 a = src[0], b = src[1];
        union { unsigned short u[8]; short8 v; } cv;
        cv.u[0] = f2bf(a.x); cv.u[1] = f2bf(a.y); cv.u[2] = f2bf(a.z); cv.u[3] = f2bf(a.w);
        cv.u[4] = f2bf(b.x); cv.u[5] = f2bf(b.y); cv.u[6] = f2bf(b.z); cv.u[7] = f2bf(b.w);
        *reinterpret_cast<short8*>((unsigned short*)web + i0) = cv.v;
        return;
    }
    // qk: q[b][k] = sum_h hidden[b][h]*Wh[k][h] + attn_b[k]
    int k = bid - (NB_ENC + NB_WE);   // 0..1023
    int tid = threadIdx.x;
    const float* w = attn_w + (size_t)k * (2 * HDIM);
    float p[BATCH];
#pragma unroll
    for (int b = 0; b < BATCH; b++) p[b] = 0.f;
    for (int h = tid; h < HDIM; h += 256) {
        float wv = w[h];
#pragma unroll
        for (int b = 0; b < BATCH; b++) p[b] += hidden[b * HDIM + h] * wv;
    }
#pragma unroll
    for (int b = 0; b < BATCH; b++) {
        for (int off = 32; off; off >>= 1) p[b] += __shfl_down(p[b], off);
    }
    __shared__ float red[4][BATCH];
    int lane = tid & 63, wid = tid >> 6;
    if (lane == 0) {
#pragma unroll
        for (int b = 0; b < BATCH; b++) red[wid][b] = p[b];
    }
    __syncthreads();
    if (tid < BATCH) {
        float s = red[0][tid] + red[1][tid] + red[2][tid] + red[3][tid] + attn_b[k];
        q[(size_t)tid * HDIM + k] = s;
    }
}

// ---------------- kernel 2: 8-phase 256x256 GEMM + fused tanh/score epilogue (round-5) ------
// LDS map (bytes): A[par][half] = par*32768 + half*16384 ; B[par][half] = 65536 + same. 128KB.
// Swizzle involution within each 128B row: byte ^= ((row&7)<<4). Applied to global src + ds_read.
__global__ __launch_bounds__(512, 2) void gemm8(const __hip_bfloat16* __restrict__ encb,
                                                const __hip_bfloat16* __restrict__ web,
                                                const float* __restrict__ qv,
                                                const float* __restrict__ score_w,
                                                float* __restrict__ part) {
    __shared__ __align__(16) char pool[131072];

    int tid = threadIdx.x;
    int lane = tid & 63;
    int wid = tid >> 6;        // 0..7
    int wr = wid >> 2;         // 0..1  M half
    int wc = wid & 3;          // 0..3  N quarter

    // XCD-bijective swizzle: 512 blocks = 8 XCDs x 64; same-bm (A-panel) blocks contiguous per XCD
    int bid = blockIdx.x;
    int lin = (bid & 7) * 64 + (bid >> 3);
    int bm = lin >> 2;         // 0..127
    int bn = lin & 3;          // 0..3
    int m0 = bm * BM, n0 = bn * BN;

    // ---- staging thread constants (pre-swizzled global source) ----
    int srow = tid >> 3;                                   // 0..63
    int scolb = (((tid & 7) ^ ((tid >> 3) & 7)) << 4);     // swizzled byte col 0..127
    const char* eb = (const char*)encb;
    const char* wb = (const char*)web;

    auto STG = [&](const char* g, int ldsoff) {
        GLD16(g + (size_t)srow * 2048 + scolb, pool + ldsoff + wid * 1024);
        GLD16(g + (size_t)(srow + 64) * 2048 + scolb, pool + ldsoff + 8192 + wid * 1024);
    };
    auto APTR = [&](int kt, int h) { return eb + ((size_t)(m0 + h * 128) * HDIM + kt * BKT) * 2; };
    auto BPTR = [&](int kt, int h) { return wb + ((size_t)(n0 + h * 128) * HDIM + kt * BKT) * 2; };
#define ALDS(par, h) ((par) * 32768 + (h) * 16384)
#define BLDS(par, h) (65536 + (par) * 32768 + (h) * 16384)

    // ---- fragment-read constants (swizzled ds_read addresses) ----
    int lq = lane & 15, lh = lane >> 4;
    int flip = (lane & 7) << 4;
    int pks0 = lq * 128 + ((lh * 16) ^ flip);
    int pks1 = lq * 128 + (((64 + lh * 16)) ^ flip);
    int aFB = wr * 16384;                                   // + par*32768
    int bFB = 65536 + (wc >> 1) * 16384 + (wc & 1) * 8192;  // + par*32768

    f32x4 acc[8][4];
#pragma unroll
    for (int i = 0; i < 8; i++)
#pragma unroll
        for (int j = 0; j < 4; j++) acc[i][j] = (f32x4)0.f;
    short8 br[4][2];

#define RD8(off) (*reinterpret_cast<const short8*>(pool + (off)))

    // phase: reads (B full at Q==0 -> regs; A quarter Q) | stage | barrier | 16 MFMA | [vmcnt] barrier
#define PHASE(Q, PAR, STAGE_STMT, PRE_CLOSE)                                              \
    {                                                                                     \
        if ((Q) == 0) {                                                                   \
            _Pragma("unroll") for (int nj = 0; nj < 4; ++nj) {                            \
                br[nj][0] = RD8(bFB + (PAR) * 32768 + nj * 2048 + pks0);                  \
                br[nj][1] = RD8(bFB + (PAR) * 32768 + nj * 2048 + pks1);                  \
            }                                                                             \
        }                                                                                 \
        short8 a0k0 = RD8(aFB + (PAR) * 32768 + (2 * (Q)) * 2048 + pks0);                 \
        short8 a0k1 = RD8(aFB + (PAR) * 32768 + (2 * (Q)) * 2048 + pks1);                 \
        short8 a1k0 = RD8(aFB + (PAR) * 32768 + (2 * (Q) + 1) * 2048 + pks0);             \
        short8 a1k1 = RD8(aFB + (PAR) * 32768 + (2 * (Q) + 1) * 2048 + pks1);             \
        STAGE_STMT;                                                                       \
        __builtin_amdgcn_s_barrier();                                                     \
        __builtin_amdgcn_s_setprio(1);                                                    \
        _Pragma("unroll") for (int nj = 0; nj < 4; ++nj) {                                \
            acc[2 * (Q)][nj] = __builtin_amdgcn_mfma_f32_16x16x32_bf16(a0k0, br[nj][0], acc[2 * (Q)][nj], 0, 0, 0); \
            acc[2 * (Q)][nj] = __builtin_amdgcn_mfma_f32_16x16x32_bf16(a0k1, br[nj][1], acc[2 * (Q)][nj], 0, 0, 0); \
            acc[2 * (Q) + 1][nj] = __builtin_amdgcn_mfma_f32_16x16x32_bf16(a1k0, br[nj][0], acc[2 * (Q) + 1][nj], 0, 0, 0); \
            acc[2 * (Q) + 1][nj] = __builtin_amdgcn_mfma_f32_16x16x32_bf16(a1k1, br[nj][1], acc[2 * (Q) + 1][nj], 0, 0, 0); \
        }                                                                                 \
        __builtin_amdgcn_s_setprio(0);                                                    \
        PRE_CLOSE;                                                                        \
        __builtin_amdgcn_s_barrier();                                                     \
        __builtin_amdgcn_sched_barrier(0);                                                \
    }

    // ---- prologue: stage B(0), A(0), B(1); land tile 0 (oldest 8 loads) ----
    STG(BPTR(0, 0), BLDS(0, 0));
    STG(BPTR(0, 1), BLDS(0, 1));
    STG(APTR(0, 0), ALDS(0, 0));
    STG(APTR(0, 1), ALDS(0, 1));
    STG(BPTR(1, 0), BLDS(1, 0));
    STG(BPTR(1, 1), BLDS(1, 1));
    VMC(4);
    __builtin_amdgcn_s_barrier();
    __builtin_amdgcn_sched_barrier(0);

    // ---- main loop: iters J=0..6 (tiles 2J,2J+1), steady staging 2 tiles ahead ----
#pragma unroll 1
    for (int J = 0; J < 7; ++J) {
        int k1 = 2 * J + 1;
        PHASE(0, 0, STG(APTR(k1, 0), ALDS(1, 0)), );
        PHASE(1, 0, STG(APTR(k1, 1), ALDS(1, 1)), );
        PHASE(2, 0, STG(BPTR(k1 + 1, 0), BLDS(0, 0)), );
        PHASE(3, 0, STG(BPTR(k1 + 1, 1), BLDS(0, 1)), VMC(4));   // lands A(k1), B(k1)
        PHASE(0, 1, STG(APTR(k1 + 1, 0), ALDS(0, 0)), );
        PHASE(1, 1, STG(APTR(k1 + 1, 1), ALDS(0, 1)), );
        PHASE(2, 1, STG(BPTR(k1 + 2, 0), BLDS(1, 0)), );
        PHASE(3, 1, STG(BPTR(k1 + 2, 1), BLDS(1, 1)), VMC(4));   // lands A(k0+2), B(k0+2)
    }
    // ---- peeled last iter (tiles 14,15): stage only A(15); drain at P4 ----
    PHASE(0, 0, STG(APTR(15, 0), ALDS(1, 0)), );
    PHASE(1, 0, STG(APTR(15, 1), ALDS(1, 1)), );
    PHASE(2, 0, , );
    PHASE(3, 0, , VMC(0));
    PHASE(0, 1, , );
    PHASE(1, 1, , );
    PHASE(2, 1, , );
    PHASE(3, 1, , );

    // ---- fused epilogue (aliases pool) ----
    float* q_lds = reinterpret_cast<float*>(pool);            // [16][256]
    float* sc_lds = reinterpret_cast<float*>(pool + 16384);   // [256]
    float* eng = reinterpret_cast<float*>(pool + 17408);      // [4][256]
    {
        int qb = tid >> 5;            // 0..15
        int kl = (tid & 31) * 8;      // 0..248
        const float4* src = reinterpret_cast<const float4*>(qv + (size_t)qb * HDIM + n0 + kl);
        float4 v0 = src[0], v1 = src[1];
        *reinterpret_cast<float4*>(&q_lds[qb * 256 + kl]) = v0;
        *reinterpret_cast<float4*>(&q_lds[qb * 256 + kl + 4]) = v1;
        if (tid < BN) sc_lds[tid] = score_w[n0 + tid];
    }
    __syncthreads();

#pragma unroll
    for (int mi = 0; mi < 8; ++mi) {
#pragma unroll
        for (int r = 0; r < 4; ++r) {
            int b = lh * 4 + r;       // row-within-16 == batch index
            float s = 0.f;
#pragma unroll
            for (int nj = 0; nj < 4; ++nj) {
                int kl = wc * 64 + nj * 16 + lq;
                float v = acc[mi][nj][r] + q_lds[b * 256 + kl];
                float t = 1.f - 2.f / (__expf(2.f * v) + 1.f);  // tanh(v)
                s += sc_lds[kl] * t;
            }
            for (int off = 1; off < 16; off <<= 1) s += __shfl_xor(s, off);
            if (lq == 0) eng[wc * 256 + wr * 128 + mi * 16 + b] = s;
        }
    }
    __syncthreads();
    if (tid < BM) {
        float s = eng[tid] + eng[256 + tid] + eng[512 + tid] + eng[768 + tid];
        part[(size_t)bn * M_TOT + m0 + tid] = s;
    }
#undef PHASE
#undef RD8
#undef ALDS
#undef BLDS
}

// ---------------- kernel 3: reduce partials + mask + softmax over S ----------------
__global__ __launch_bounds__(256) void softmax_kernel(const float* __restrict__ part,
                                                      const int* __restrict__ mask,
                                                      float* __restrict__ out) {
    int b = blockIdx.x;
    int tid = threadIdx.x;
    __shared__ float e_lds[SEQ];
    __shared__ float red[4], red2[4];
    int lane = tid & 63, wid = tid >> 6;
    float lmax = -3.4e38f;
    for (int it = 0; it < SEQ / 256; ++it) {
        int s = it * 256 + tid;
        size_t m = (size_t)s * BATCH + b;
        float e = 0.f;
#pragma unroll
        for (int c = 0; c < NBLK; c++) e += part[(size_t)c * M_TOT + m];
        if (mask[(size_t)b * SEQ + s]) e = -1e12f;
        e_lds[s] = e;
        lmax = fmaxf(lmax, e);
    }
    for (int off = 32; off; off >>= 1) lmax = fmaxf(lmax, __shfl_xor(lmax, off));
    if (lane == 0) red[wid] = lmax;
    __syncthreads();
    float gmax = fmaxf(fmaxf(red[0], red[1]), fmaxf(red[2], red[3]));
    float lsum = 0.f;
    for (int it = 0; it < SEQ / 256; ++it) {
        int s = it * 256 + tid;
        float p = __expf(e_lds[s] - gmax);
        e_lds[s] = p;
        lsum += p;
    }
    for (int off = 32; off; off >>= 1) lsum += __shfl_xor(lsum, off);
    if (lane == 0) red2[wid] = lsum;
    __syncthreads();
    float inv = 1.f / (red2[0] + red2[1] + red2[2] + red2[3]);
    for (int it = 0; it < SEQ / 256; ++it) {
        int s = it * 256 + tid;
        out[(size_t)b * SEQ + s] = e_lds[s] * inv;
    }
}

extern "C" void kernel_launch(void* const* d_in, const int* in_sizes, int n_in,
                              void* d_out, int out_size, void* d_ws, size_t ws_size,
                              hipStream_t stream) {
    const float* hidden   = (const float*)d_in[0];
    const float* enc      = (const float*)d_in[1];
    const int*   seq_mask = (const int*)d_in[2];
    const float* attn_w   = (const float*)d_in[3];
    const float* attn_b   = (const float*)d_in[4];
    const float* score_w  = (const float*)d_in[5];
    float* out = (float*)d_out;

    char* ws = (char*)d_ws;
    float* q = (float*)ws;                                        // 64 KB
    __hip_bfloat16* web = (__hip_bfloat16*)(ws + 65536);          // 2 MB
    float* part = (float*)(ws + 65536 + 2 * 1024 * 1024);         // 512 KB
    __hip_bfloat16* encb = (__hip_bfloat16*)(ws + 65536 + 3 * 1024 * 1024);  // 64 MB

    prep_all<<<dim3(NB_ENC + NB_WE + NB_QK), dim3(256), 0, stream>>>(hidden, enc, attn_w, attn_b, q, web, encb);
    gemm8<<<dim3(NBLK * (M_TOT / BM)), dim3(512), 0, stream>>>(encb, web, q, score_w, part);
    softmax_kernel<<<dim3(BATCH), dim3(256), 0, stream>>>(part, seq_mask, out);
}